// Round 7
// baseline (551.106 us; speedup 1.0000x reference)
//
#include <hip/hip_runtime.h>
#include <math.h>

#define N_NODES 100000
#define N_EDGES 1600000
#define F_IN    64
#define H       32
#define C       2
#define G       500
#define BN_EPS  1e-5f

// ---------------------------------------------------------------- zero utils
__global__ __launch_bounds__(256) void k_zero_f(float* __restrict__ p, int n) {
    int i = blockIdx.x * 256 + threadIdx.x;
    if (i < n) p[i] = 0.f;
}
__global__ __launch_bounds__(256) void k_zero_i(int* __restrict__ p, int n) {
    int i = blockIdx.x * 256 + threadIdx.x;
    if (i < n) p[i] = 0;
}

// ------------------------------------------------------- CSR build: histogram
__global__ __launch_bounds__(256) void k_hist(
    const int* __restrict__ ei, int* __restrict__ deg)
{
    int e = blockIdx.x * 256 + threadIdx.x;
    if (e < N_EDGES) atomicAdd(&deg[ei[N_EDGES + e]], 1);
}

// block-level exclusive scan (in place on rowptr), block totals to bsum
__global__ __launch_bounds__(256) void k_scan1(
    int* __restrict__ rowptr, int* __restrict__ bsum)
{
    __shared__ int s[256];
    int i = blockIdx.x * 256 + threadIdx.x;
    int v = (i < N_NODES) ? rowptr[i] : 0;
    s[threadIdx.x] = v;
    __syncthreads();
    for (int off = 1; off < 256; off <<= 1) {
        int t = (threadIdx.x >= off) ? s[threadIdx.x - off] : 0;
        __syncthreads();
        s[threadIdx.x] += t;
        __syncthreads();
    }
    if (i < N_NODES) rowptr[i] = s[threadIdx.x] - v;   // exclusive within block
    if (threadIdx.x == 255) bsum[blockIdx.x] = s[255];
}

// single-block scan of block sums (nb <= 512), exclusive in place
__global__ __launch_bounds__(512) void k_scan2(int* __restrict__ bsum, int nb)
{
    __shared__ int s[512];
    int i = threadIdx.x;
    int v = (i < nb) ? bsum[i] : 0;
    s[i] = v;
    __syncthreads();
    for (int off = 1; off < 512; off <<= 1) {
        int t = (i >= off) ? s[i - off] : 0;
        __syncthreads();
        s[i] += t;
        __syncthreads();
    }
    if (i < nb) bsum[i] = s[i] - v;
}

// add block offsets; init cursor; set rowptr[N]=E
__global__ __launch_bounds__(256) void k_scan3(
    int* __restrict__ rowptr, const int* __restrict__ bsum,
    int* __restrict__ cursor)
{
    int i = blockIdx.x * 256 + threadIdx.x;
    if (i < N_NODES) {
        int r = rowptr[i] + bsum[i >> 8];
        rowptr[i] = r;
        cursor[i] = r;
    }
    if (i == 0) rowptr[N_NODES] = N_EDGES;
}

// scatter src ids into CSR adjacency
__global__ __launch_bounds__(256) void k_scatter(
    const int* __restrict__ ei, int* __restrict__ cursor,
    int* __restrict__ elist)
{
    int e = blockIdx.x * 256 + threadIdx.x;
    if (e < N_EDGES) {
        int d = ei[N_EDGES + e];
        int pos = atomicAdd(&cursor[d], 1);
        elist[pos] = ei[e];
    }
}

// ------------------------------------------------- y0 = x @ W1^T
__global__ __launch_bounds__(256) void k_xform0(
    const float* __restrict__ x, const float* __restrict__ W1,
    float* __restrict__ y)
{
    __shared__ float Wt[F_IN * H];   // Wt[k*H+f] = W1[f*F_IN+k]
    __shared__ float xs[8 * F_IN];
    int tid = threadIdx.x;
    for (int idx = tid; idx < F_IN * H; idx += 256) {
        int f = idx & (H - 1);
        int k = idx >> 5;
        Wt[k * H + f] = W1[f * F_IN + k];
    }
    int n0 = blockIdx.x * 8;
    for (int idx = tid; idx < 8 * F_IN; idx += 256) {
        int nl = idx >> 6, k = idx & 63;
        int n = n0 + nl;
        xs[idx] = (n < N_NODES) ? x[n * F_IN + k] : 0.f;
    }
    __syncthreads();
    int nl = tid >> 5, f = tid & 31;
    int n = n0 + nl;
    if (n < N_NODES) {
        float acc = 0.f;
#pragma unroll
        for (int k = 0; k < F_IN; ++k) acc += xs[nl * F_IN + k] * Wt[k * H + f];
        y[n * H + f] = acc;
    }
}

// -------------------------- agg[n] = y[n] + sum_{s in adj(n)} y[s]  (float4)
__global__ __launch_bounds__(256) void k_agg(
    const int* __restrict__ rowptr, const int* __restrict__ elist,
    const float* __restrict__ y, float* __restrict__ out)
{
    int t = blockIdx.x * 256 + threadIdx.x;
    int n = t >> 3;
    int q = t & 7;
    if (n >= N_NODES) return;
    int j  = rowptr[n];
    int j1 = rowptr[n + 1];
    const float4* y4 = (const float4*)y;
    float4 a = y4[n * 8 + q];          // self term
    float4 b = make_float4(0.f, 0.f, 0.f, 0.f);
    float4 c = make_float4(0.f, 0.f, 0.f, 0.f);
    float4 d = make_float4(0.f, 0.f, 0.f, 0.f);
    for (; j + 4 <= j1; j += 4) {
        int s0 = elist[j],     s1 = elist[j + 1];
        int s2 = elist[j + 2], s3 = elist[j + 3];
        float4 v0 = y4[s0 * 8 + q];
        float4 v1 = y4[s1 * 8 + q];
        float4 v2 = y4[s2 * 8 + q];
        float4 v3 = y4[s3 * 8 + q];
        a.x += v0.x; a.y += v0.y; a.z += v0.z; a.w += v0.w;
        b.x += v1.x; b.y += v1.y; b.z += v1.z; b.w += v1.w;
        c.x += v2.x; c.y += v2.y; c.z += v2.z; c.w += v2.w;
        d.x += v3.x; d.y += v3.y; d.z += v3.z; d.w += v3.w;
    }
    for (; j < j1; ++j) {
        int s0 = elist[j];
        float4 v0 = y4[s0 * 8 + q];
        a.x += v0.x; a.y += v0.y; a.z += v0.z; a.w += v0.w;
    }
    a.x += b.x + c.x + d.x;
    a.y += b.y + c.y + d.y;
    a.z += b.z + c.z + d.z;
    a.w += b.w + c.w + d.w;
    ((float4*)out)[n * 8 + q] = a;
}

// ---- layer0 epilogue: t=relu(agg+b1); z=t@W2^T+b2; h=bn(relu(z)); y1=h@nW^T
__global__ __launch_bounds__(256) void k_mlp0(
    const float* __restrict__ agg_in,
    const float* __restrict__ b1, const float* __restrict__ W2,
    const float* __restrict__ b2,
    const float* __restrict__ gamma, const float* __restrict__ beta,
    const float* __restrict__ mean,  const float* __restrict__ var,
    const float* __restrict__ nW,
    float* __restrict__ y_out)
{
    __shared__ float W2t[H * H];
    __shared__ float nWt[H * H];
    __shared__ float tb[8][H];
    __shared__ float hb[8][H];
    int tid = threadIdx.x;
    for (int idx = tid; idx < H * H; idx += 256) {
        int f = idx & 31, k = idx >> 5;
        W2t[k * H + f] = W2[f * H + k];
        nWt[k * H + f] = nW[f * H + k];
    }
    int n0 = blockIdx.x * 8;
    int nl = tid >> 5, f = tid & 31;
    int n = n0 + nl;
    bool ok = n < N_NODES;
    float tv = 0.f;
    if (ok) tv = fmaxf(agg_in[n * H + f] + b1[f], 0.f);
    tb[nl][f] = tv;
    __syncthreads();
    float z = b2[f];
#pragma unroll
    for (int k = 0; k < H; ++k) z += tb[nl][k] * W2t[k * H + f];
    z = fmaxf(z, 0.f);
    float s  = gamma[f] * rsqrtf(var[f] + BN_EPS);
    float hv = (z - mean[f]) * s + beta[f];
    hb[nl][f] = hv;
    __syncthreads();
    float yv = 0.f;
#pragma unroll
    for (int k = 0; k < H; ++k) yv += hb[nl][k] * nWt[k * H + f];
    if (ok) y_out[n * H + f] = yv;
}

// ---- layer1 epilogue + global_add_pool (segment-head combining, batch sorted)
__global__ __launch_bounds__(256) void k_mlp1_pool(
    const float* __restrict__ agg_in, const int* __restrict__ batch,
    const float* __restrict__ b1, const float* __restrict__ W2,
    const float* __restrict__ b2,
    const float* __restrict__ gamma, const float* __restrict__ beta,
    const float* __restrict__ mean,  const float* __restrict__ var,
    float* __restrict__ gpool)
{
    __shared__ float W2t[H * H];
    __shared__ float tb[8][H];
    __shared__ float hb[8][H];
    __shared__ int   bs[8];
    int tid = threadIdx.x;
    for (int idx = tid; idx < H * H; idx += 256) {
        int f = idx & 31, k = idx >> 5;
        W2t[k * H + f] = W2[f * H + k];
    }
    int n0 = blockIdx.x * 8;
    if (tid < 8) {
        int n = n0 + tid;
        bs[tid] = (n < N_NODES) ? batch[n] : -1;
    }
    int nl = tid >> 5, f = tid & 31;
    int n = n0 + nl;
    bool ok = n < N_NODES;
    float tv = 0.f;
    if (ok) tv = fmaxf(agg_in[n * H + f] + b1[f], 0.f);
    tb[nl][f] = tv;
    __syncthreads();
    float z = b2[f];
#pragma unroll
    for (int k = 0; k < H; ++k) z += tb[nl][k] * W2t[k * H + f];
    z = fmaxf(z, 0.f);
    float s  = gamma[f] * rsqrtf(var[f] + BN_EPS);
    float hv = (z - mean[f]) * s + beta[f];
    hb[nl][f] = hv;
    __syncthreads();
    if (ok && (nl == 0 || bs[nl] != bs[nl - 1])) {
        int bid = bs[nl];
        float acc = hv;
        for (int j = nl + 1; j < 8 && bs[j] == bid; ++j) acc += hb[j][f];
        atomicAdd(&gpool[bid * H + f], acc);
    }
}

// -------------------- g -> relu(fc1) -> fc2 -> seq[G*C]
__global__ __launch_bounds__(256) void k_fc(
    const float* __restrict__ gpool,
    const float* __restrict__ fc1W, const float* __restrict__ fc1b,
    const float* __restrict__ fc2W, const float* __restrict__ fc2b,
    float* __restrict__ seq)
{
    __shared__ float W1t[H * H];
    __shared__ float gs[8][H];
    __shared__ float tb[8][H];
    int tid = threadIdx.x;
    for (int idx = tid; idx < H * H; idx += 256) {
        int f = idx & 31, k = idx >> 5;
        W1t[k * H + f] = fc1W[f * H + k];
    }
    int n0 = blockIdx.x * 8;
    int nl = tid >> 5, f = tid & 31;
    int g = n0 + nl;
    bool ok = g < G;
    gs[nl][f] = ok ? gpool[g * H + f] : 0.f;
    __syncthreads();
    float z = fc1b[f];
#pragma unroll
    for (int k = 0; k < H; ++k) z += gs[nl][k] * W1t[k * H + f];
    tb[nl][f] = fmaxf(z, 0.f);
    __syncthreads();
    if (ok && f < C) {
        float z2 = fc2b[f];
#pragma unroll
        for (int k = 0; k < H; ++k) z2 += tb[nl][k] * fc2W[f * H + k];
        seq[g * C + f] = z2;
    }
}

// ---------- wave-synchronous bidirectional LSTM ----------
// 1 wave per direction, zero barriers in the time loop.
// Weights pinned in VGPRs via empty inline-asm (defeats load-remat).
// Gate exchange via __shfl_xor(.,32) + select — VERIFIED correct in round 4.
// (permlane32_swap direction was guessed wrong twice; reverted for good.)

#if __has_builtin(__builtin_amdgcn_readlane)
#define RDL(v, k) __int_as_float(__builtin_amdgcn_readlane(__float_as_int(v), (k)))
#else
#define RDL(v, k) __shfl((v), (k), 64)
#endif

#define LOG2E  1.4426950408889634f
#define N2L2E  2.8853900817779268f

#if __has_builtin(__builtin_amdgcn_exp2f) && __has_builtin(__builtin_amdgcn_rcpf)
#define EXP2F(x) __builtin_amdgcn_exp2f(x)
#define RCPF(x)  __builtin_amdgcn_rcpf(x)
#else
#define EXP2F(x) exp2f(x)
#define RCPF(x)  (1.f / (x))
#endif

__device__ __forceinline__ float fsig(float x) {   // 1/(1+e^-x)
    return RCPF(1.f + EXP2F(-LOG2E * x));
}
__device__ __forceinline__ float ftanh(float x) {  // 2/(1+e^-2x) - 1
    return 2.f * RCPF(1.f + EXP2F(-N2L2E * x)) - 1.f;
}

// pin a float4's components into VGPRs (asm output is not rematerializable)
#define PIN4(v) asm("" : "+v"((v).x), "+v"((v).y), "+v"((v).z), "+v"((v).w))
#define PIN1(v) asm("" : "+v"(v))

// accumulate 4 k-slots: literal J in [0,7]
#define ACC4(J, av, bv)                                                   \
    {                                                                     \
        float h0 = RDL(hval, 4 * (J));                                    \
        float h1 = RDL(hval, 4 * (J) + 1);                                \
        float h2 = RDL(hval, 4 * (J) + 2);                                \
        float h3 = RDL(hval, 4 * (J) + 3);                                \
        z0 = fmaf(av.x, h0, z0); z1 = fmaf(av.y, h1, z1);                 \
        z2 = fmaf(av.z, h2, z2); z3 = fmaf(av.w, h3, z3);                 \
        y0 = fmaf(bv.x, h0, y0); y1 = fmaf(bv.y, h1, y1);                 \
        y2 = fmaf(bv.z, h2, y2); y3 = fmaf(bv.w, h3, y3);                 \
    }

__global__ __launch_bounds__(128, 1) void k_lstm(
    const float* __restrict__ seq,
    const float* __restrict__ Wih_f, const float* __restrict__ Whh_f,
    const float* __restrict__ bih_f, const float* __restrict__ bhh_f,
    const float* __restrict__ Wih_b, const float* __restrict__ Whh_b,
    const float* __restrict__ bih_b, const float* __restrict__ bhh_b,
    const float* __restrict__ redW, const float* __restrict__ redb,
    float* __restrict__ out)
{
    __shared__ float sq[G * C];
    __shared__ float hl[2][H];
    int tid  = threadIdx.x;
    int dir  = tid >> 6;       // wave 0 = forward, wave 1 = backward
    int lane = tid & 63;

    for (int i = tid; i < G * C; i += 128) sq[i] = seq[i];
    __syncthreads();

    const float* Wih = dir ? Wih_b : Wih_f;
    const float* Whh = dir ? Whh_b : Whh_f;
    const float* bih = dir ? bih_b : bih_f;
    const float* bhh = dir ? bhh_b : bhh_f;

    // lane l owns gate rows ra=l (i rows 0..31 | f rows 32..63)
    //                    and rb=l+64 (g rows 64..95 | o rows 96..127)
    int ra = lane;
    int rb = lane + 64;
    bool hi = lane >= 32;

    const float4* Wa4 = (const float4*)&Whh[ra * H];
    const float4* Wb4 = (const float4*)&Whh[rb * H];
    float4 a0 = Wa4[0], a1 = Wa4[1], a2 = Wa4[2], a3 = Wa4[3];
    float4 a4 = Wa4[4], a5 = Wa4[5], a6 = Wa4[6], a7 = Wa4[7];
    float4 b0 = Wb4[0], b1 = Wb4[1], b2 = Wb4[2], b3 = Wb4[3];
    float4 b4 = Wb4[4], b5 = Wb4[5], b6 = Wb4[6], b7 = Wb4[7];
    PIN4(a0); PIN4(a1); PIN4(a2); PIN4(a3);
    PIN4(a4); PIN4(a5); PIN4(a6); PIN4(a7);
    PIN4(b0); PIN4(b1); PIN4(b2); PIN4(b3);
    PIN4(b4); PIN4(b5); PIN4(b6); PIN4(b7);

    float wia0 = Wih[ra * C], wia1 = Wih[ra * C + 1];
    float wib0 = Wih[rb * C], wib1 = Wih[rb * C + 1];
    float bza  = bih[ra] + bhh[ra];
    float bzb  = bih[rb] + bhh[rb];
    PIN1(wia0); PIN1(wia1); PIN1(wib0); PIN1(wib1);
    PIN1(bza);  PIN1(bzb);

    float hval = 0.f;     // replicated: lane holds h[lane&31]
    float cst  = 0.f;     // replicated cell state

    // software-pipelined sq reads
    int tt0 = dir ? (G - 1) : 0;
    float x0 = sq[tt0 * C];
    float x1 = sq[tt0 * C + 1];

    for (int t = 0; t < G; ++t) {
        int tn = (t + 1 < G) ? (dir ? (G - 2 - t) : (t + 1)) : 0;
        float nx0 = sq[tn * C];
        float nx1 = sq[tn * C + 1];

        float z0 = 0.f, z1 = 0.f, z2 = 0.f, z3 = 0.f;
        float y0 = 0.f, y1 = 0.f, y2 = 0.f, y3 = 0.f;
        ACC4(0, a0, b0); ACC4(1, a1, b1); ACC4(2, a2, b2); ACC4(3, a3, b3);
        ACC4(4, a4, b4); ACC4(5, a5, b5); ACC4(6, a6, b6); ACC4(7, a7, b7);
        float za = bza + fmaf(wia0, x0, fmaf(wia1, x1, (z0 + z1) + (z2 + z3)));
        float zb = bzb + fmaf(wib0, x0, fmaf(wib1, x1, (y0 + y1) + (y2 + y3)));

        // za: lanes 0..31 = i-rows, lanes 32..63 = f-rows
        // zb: lanes 0..31 = g-rows, lanes 32..63 = o-rows
        float zax = __shfl_xor(za, 32, 64);
        float zbx = __shfl_xor(zb, 32, 64);
        float zi = hi ? zax : za;
        float zf = hi ? za  : zax;
        float zg = hi ? zbx : zb;
        float zo = hi ? zb  : zbx;

        cst  = fsig(zf) * cst + fsig(zi) * ftanh(zg);
        hval = fsig(zo) * ftanh(cst);

        x0 = nx0; x1 = nx1;
    }

    if (lane < H) hl[dir][lane] = hval;
    __syncthreads();

    if (tid == 0) {
        float v0 = redb[0], v1 = redb[1];
        for (int k = 0; k < H; ++k) {
            v0 += hl[0][k] * redW[k]         + hl[1][k] * redW[H + k];
            v1 += hl[0][k] * redW[2 * H + k] + hl[1][k] * redW[3 * H + k];
        }
        v0 = fmaxf(v0, 0.f);
        v1 = fmaxf(v1, 0.f);
        float m = fmaxf(v0, v1);
        float l = logf(expf(v0 - m) + expf(v1 - m));
        out[0] = v0 - m - l;
        out[1] = v1 - m - l;
    }
}

extern "C" void kernel_launch(void* const* d_in, const int* in_sizes, int n_in,
                              void* d_out, int out_size, void* d_ws, size_t ws_size,
                              hipStream_t stream) {
    const float* x        = (const float*)d_in[0];
    const int*   ei       = (const int*)  d_in[1];
    const int*   batch    = (const int*)  d_in[2];
    const float* gin0_W1  = (const float*)d_in[3];
    const float* gin0_b1  = (const float*)d_in[4];
    const float* gin0_W2  = (const float*)d_in[5];
    const float* gin0_b2  = (const float*)d_in[6];
    const float* bn0_g    = (const float*)d_in[7];
    const float* bn0_b    = (const float*)d_in[8];
    const float* bn0_m    = (const float*)d_in[9];
    const float* bn0_v    = (const float*)d_in[10];
    const float* gin1_W1  = (const float*)d_in[11];
    const float* gin1_b1  = (const float*)d_in[12];
    const float* gin1_W2  = (const float*)d_in[13];
    const float* gin1_b2  = (const float*)d_in[14];
    const float* bn1_g    = (const float*)d_in[15];
    const float* bn1_b    = (const float*)d_in[16];
    const float* bn1_m    = (const float*)d_in[17];
    const float* bn1_v    = (const float*)d_in[18];
    const float* fc1_W    = (const float*)d_in[19];
    const float* fc1_b    = (const float*)d_in[20];
    const float* fc2_W    = (const float*)d_in[21];
    const float* fc2_b    = (const float*)d_in[22];
    const float* Wih_f    = (const float*)d_in[23];
    const float* Whh_f    = (const float*)d_in[24];
    const float* bih_f    = (const float*)d_in[25];
    const float* bhh_f    = (const float*)d_in[26];
    const float* Wih_b    = (const float*)d_in[27];
    const float* Whh_b    = (const float*)d_in[28];
    const float* bih_b    = (const float*)d_in[29];
    const float* bhh_b    = (const float*)d_in[30];
    const float* red_W    = (const float*)d_in[31];
    const float* red_b    = (const float*)d_in[32];

    // workspace layout
    float* ws    = (float*)d_ws;
    float* A     = ws;                          // y buffer   N*H
    float* B     = A + (size_t)N_NODES * H;     // agg buffer N*H
    float* gpool = B + (size_t)N_NODES * H;     // G*H
    float* seq   = gpool + (size_t)G * H;       // G*C
    int*   rowptr = (int*)(seq + (size_t)G * C);        // N+1
    int*   cursor = rowptr + (N_NODES + 1);             // N
    int*   bsum   = cursor + N_NODES;                   // 1024
    int*   elist  = bsum + 1024;                        // E

    int nblk_nodes = (N_NODES + 7) / 8;          // 12500 (8 nodes/block)
    int nblk_edges = (N_EDGES + 255) / 256;      // 6250
    int nblk_scan  = (N_NODES + 255) / 256;      // 391
    int nblk_agg   = (N_NODES * 8 + 255) / 256;  // 3125

    // ---- CSR build (once; reused by both layers)
    k_zero_i<<<nblk_scan, 256, 0, stream>>>(rowptr, N_NODES);
    k_hist<<<nblk_edges, 256, 0, stream>>>(ei, rowptr);
    k_scan1<<<nblk_scan, 256, 0, stream>>>(rowptr, bsum);
    k_scan2<<<1, 512, 0, stream>>>(bsum, nblk_scan);
    k_scan3<<<nblk_scan, 256, 0, stream>>>(rowptr, bsum, cursor);
    k_scatter<<<nblk_edges, 256, 0, stream>>>(ei, cursor, elist);

    k_zero_f<<<(G * H + 255) / 256, 256, 0, stream>>>(gpool, G * H);

    // ---- layer 0
    k_xform0<<<nblk_nodes, 256, 0, stream>>>(x, gin0_W1, A);
    k_agg<<<nblk_agg, 256, 0, stream>>>(rowptr, elist, A, B);
    k_mlp0<<<nblk_nodes, 256, 0, stream>>>(B, gin0_b1, gin0_W2, gin0_b2,
                                           bn0_g, bn0_b, bn0_m, bn0_v,
                                           gin1_W1, A);
    // ---- layer 1
    k_agg<<<nblk_agg, 256, 0, stream>>>(rowptr, elist, A, B);
    k_mlp1_pool<<<nblk_nodes, 256, 0, stream>>>(B, batch, gin1_b1, gin1_W2,
                                                gin1_b2, bn1_g, bn1_b, bn1_m,
                                                bn1_v, gpool);
    // ---- dense tail
    k_fc<<<(G + 7) / 8, 256, 0, stream>>>(gpool, fc1_W, fc1_b, fc2_W, fc2_b, seq);
    k_lstm<<<1, 128, 0, stream>>>(seq, Wih_f, Whh_f, bih_f, bhh_f,
                                  Wih_b, Whh_b, bih_b, bhh_b,
                                  red_W, red_b, (float*)d_out);
}

// Round 8
// 534.097 us; speedup vs baseline: 1.0318x; 1.0318x over previous
//
#include <hip/hip_runtime.h>
#include <math.h>

#define N_NODES 100000
#define N_EDGES 1600000
#define F_IN    64
#define H       32
#define C       2
#define G       500
#define BN_EPS  1e-5f

// ---------------------------------------------------------------- zero utils
__global__ __launch_bounds__(256) void k_zero_f(float* __restrict__ p, int n) {
    int i = blockIdx.x * 256 + threadIdx.x;
    if (i < n) p[i] = 0.f;
}
__global__ __launch_bounds__(256) void k_zero_i(int* __restrict__ p, int n) {
    int i = blockIdx.x * 256 + threadIdx.x;
    if (i < n) p[i] = 0;
}

// ------------------------------------------------------- CSR build: histogram
__global__ __launch_bounds__(256) void k_hist(
    const int* __restrict__ ei, int* __restrict__ deg)
{
    int e = blockIdx.x * 256 + threadIdx.x;
    if (e < N_EDGES) atomicAdd(&deg[ei[N_EDGES + e]], 1);
}

// block-level exclusive scan (in place on rowptr), block totals to bsum
__global__ __launch_bounds__(256) void k_scan1(
    int* __restrict__ rowptr, int* __restrict__ bsum)
{
    __shared__ int s[256];
    int i = blockIdx.x * 256 + threadIdx.x;
    int v = (i < N_NODES) ? rowptr[i] : 0;
    s[threadIdx.x] = v;
    __syncthreads();
    for (int off = 1; off < 256; off <<= 1) {
        int t = (threadIdx.x >= off) ? s[threadIdx.x - off] : 0;
        __syncthreads();
        s[threadIdx.x] += t;
        __syncthreads();
    }
    if (i < N_NODES) rowptr[i] = s[threadIdx.x] - v;   // exclusive within block
    if (threadIdx.x == 255) bsum[blockIdx.x] = s[255];
}

// single-block scan of block sums (nb <= 512), exclusive in place
__global__ __launch_bounds__(512) void k_scan2(int* __restrict__ bsum, int nb)
{
    __shared__ int s[512];
    int i = threadIdx.x;
    int v = (i < nb) ? bsum[i] : 0;
    s[i] = v;
    __syncthreads();
    for (int off = 1; off < 512; off <<= 1) {
        int t = (i >= off) ? s[i - off] : 0;
        __syncthreads();
        s[i] += t;
        __syncthreads();
    }
    if (i < nb) bsum[i] = s[i] - v;
}

// add block offsets; init cursor; set rowptr[N]=E
__global__ __launch_bounds__(256) void k_scan3(
    int* __restrict__ rowptr, const int* __restrict__ bsum,
    int* __restrict__ cursor)
{
    int i = blockIdx.x * 256 + threadIdx.x;
    if (i < N_NODES) {
        int r = rowptr[i] + bsum[i >> 8];
        rowptr[i] = r;
        cursor[i] = r;
    }
    if (i == 0) rowptr[N_NODES] = N_EDGES;
}

// scatter src ids into CSR adjacency
__global__ __launch_bounds__(256) void k_scatter(
    const int* __restrict__ ei, int* __restrict__ cursor,
    int* __restrict__ elist)
{
    int e = blockIdx.x * 256 + threadIdx.x;
    if (e < N_EDGES) {
        int d = ei[N_EDGES + e];
        int pos = atomicAdd(&cursor[d], 1);
        elist[pos] = ei[e];
    }
}

// ------------------------------------------------- y0 = x @ W1^T
__global__ __launch_bounds__(256) void k_xform0(
    const float* __restrict__ x, const float* __restrict__ W1,
    float* __restrict__ y)
{
    __shared__ float Wt[F_IN * H];   // Wt[k*H+f] = W1[f*F_IN+k]
    __shared__ float xs[8 * F_IN];
    int tid = threadIdx.x;
    for (int idx = tid; idx < F_IN * H; idx += 256) {
        int f = idx & (H - 1);
        int k = idx >> 5;
        Wt[k * H + f] = W1[f * F_IN + k];
    }
    int n0 = blockIdx.x * 8;
    for (int idx = tid; idx < 8 * F_IN; idx += 256) {
        int nl = idx >> 6, k = idx & 63;
        int n = n0 + nl;
        xs[idx] = (n < N_NODES) ? x[n * F_IN + k] : 0.f;
    }
    __syncthreads();
    int nl = tid >> 5, f = tid & 31;
    int n = n0 + nl;
    if (n < N_NODES) {
        float acc = 0.f;
#pragma unroll
        for (int k = 0; k < F_IN; ++k) acc += xs[nl * F_IN + k] * Wt[k * H + f];
        y[n * H + f] = acc;
    }
}

// -------------------------- agg[n] = y[n] + sum_{s in adj(n)} y[s]  (float4)
__global__ __launch_bounds__(256) void k_agg(
    const int* __restrict__ rowptr, const int* __restrict__ elist,
    const float* __restrict__ y, float* __restrict__ out)
{
    int t = blockIdx.x * 256 + threadIdx.x;
    int n = t >> 3;
    int q = t & 7;
    if (n >= N_NODES) return;
    int j  = rowptr[n];
    int j1 = rowptr[n + 1];
    const float4* y4 = (const float4*)y;
    float4 a = y4[n * 8 + q];          // self term
    float4 b = make_float4(0.f, 0.f, 0.f, 0.f);
    float4 c = make_float4(0.f, 0.f, 0.f, 0.f);
    float4 d = make_float4(0.f, 0.f, 0.f, 0.f);
    for (; j + 4 <= j1; j += 4) {
        int s0 = elist[j],     s1 = elist[j + 1];
        int s2 = elist[j + 2], s3 = elist[j + 3];
        float4 v0 = y4[s0 * 8 + q];
        float4 v1 = y4[s1 * 8 + q];
        float4 v2 = y4[s2 * 8 + q];
        float4 v3 = y4[s3 * 8 + q];
        a.x += v0.x; a.y += v0.y; a.z += v0.z; a.w += v0.w;
        b.x += v1.x; b.y += v1.y; b.z += v1.z; b.w += v1.w;
        c.x += v2.x; c.y += v2.y; c.z += v2.z; c.w += v2.w;
        d.x += v3.x; d.y += v3.y; d.z += v3.z; d.w += v3.w;
    }
    for (; j < j1; ++j) {
        int s0 = elist[j];
        float4 v0 = y4[s0 * 8 + q];
        a.x += v0.x; a.y += v0.y; a.z += v0.z; a.w += v0.w;
    }
    a.x += b.x + c.x + d.x;
    a.y += b.y + c.y + d.y;
    a.z += b.z + c.z + d.z;
    a.w += b.w + c.w + d.w;
    ((float4*)out)[n * 8 + q] = a;
}

// ---- layer0 epilogue: t=relu(agg+b1); z=t@W2^T+b2; h=bn(relu(z)); y1=h@nW^T
__global__ __launch_bounds__(256) void k_mlp0(
    const float* __restrict__ agg_in,
    const float* __restrict__ b1, const float* __restrict__ W2,
    const float* __restrict__ b2,
    const float* __restrict__ gamma, const float* __restrict__ beta,
    const float* __restrict__ mean,  const float* __restrict__ var,
    const float* __restrict__ nW,
    float* __restrict__ y_out)
{
    __shared__ float W2t[H * H];
    __shared__ float nWt[H * H];
    __shared__ float tb[8][H];
    __shared__ float hb[8][H];
    int tid = threadIdx.x;
    for (int idx = tid; idx < H * H; idx += 256) {
        int f = idx & 31, k = idx >> 5;
        W2t[k * H + f] = W2[f * H + k];
        nWt[k * H + f] = nW[f * H + k];
    }
    int n0 = blockIdx.x * 8;
    int nl = tid >> 5, f = tid & 31;
    int n = n0 + nl;
    bool ok = n < N_NODES;
    float tv = 0.f;
    if (ok) tv = fmaxf(agg_in[n * H + f] + b1[f], 0.f);
    tb[nl][f] = tv;
    __syncthreads();
    float z = b2[f];
#pragma unroll
    for (int k = 0; k < H; ++k) z += tb[nl][k] * W2t[k * H + f];
    z = fmaxf(z, 0.f);
    float s  = gamma[f] * rsqrtf(var[f] + BN_EPS);
    float hv = (z - mean[f]) * s + beta[f];
    hb[nl][f] = hv;
    __syncthreads();
    float yv = 0.f;
#pragma unroll
    for (int k = 0; k < H; ++k) yv += hb[nl][k] * nWt[k * H + f];
    if (ok) y_out[n * H + f] = yv;
}

// ---- layer1 epilogue + global_add_pool (segment-head combining, batch sorted)
__global__ __launch_bounds__(256) void k_mlp1_pool(
    const float* __restrict__ agg_in, const int* __restrict__ batch,
    const float* __restrict__ b1, const float* __restrict__ W2,
    const float* __restrict__ b2,
    const float* __restrict__ gamma, const float* __restrict__ beta,
    const float* __restrict__ mean,  const float* __restrict__ var,
    float* __restrict__ gpool)
{
    __shared__ float W2t[H * H];
    __shared__ float tb[8][H];
    __shared__ float hb[8][H];
    __shared__ int   bs[8];
    int tid = threadIdx.x;
    for (int idx = tid; idx < H * H; idx += 256) {
        int f = idx & 31, k = idx >> 5;
        W2t[k * H + f] = W2[f * H + k];
    }
    int n0 = blockIdx.x * 8;
    if (tid < 8) {
        int n = n0 + tid;
        bs[tid] = (n < N_NODES) ? batch[n] : -1;
    }
    int nl = tid >> 5, f = tid & 31;
    int n = n0 + nl;
    bool ok = n < N_NODES;
    float tv = 0.f;
    if (ok) tv = fmaxf(agg_in[n * H + f] + b1[f], 0.f);
    tb[nl][f] = tv;
    __syncthreads();
    float z = b2[f];
#pragma unroll
    for (int k = 0; k < H; ++k) z += tb[nl][k] * W2t[k * H + f];
    z = fmaxf(z, 0.f);
    float s  = gamma[f] * rsqrtf(var[f] + BN_EPS);
    float hv = (z - mean[f]) * s + beta[f];
    hb[nl][f] = hv;
    __syncthreads();
    if (ok && (nl == 0 || bs[nl] != bs[nl - 1])) {
        int bid = bs[nl];
        float acc = hv;
        for (int j = nl + 1; j < 8 && bs[j] == bid; ++j) acc += hb[j][f];
        atomicAdd(&gpool[bid * H + f], acc);
    }
}

// -------------------- g -> relu(fc1) -> fc2 -> seq[G*C]
__global__ __launch_bounds__(256) void k_fc(
    const float* __restrict__ gpool,
    const float* __restrict__ fc1W, const float* __restrict__ fc1b,
    const float* __restrict__ fc2W, const float* __restrict__ fc2b,
    float* __restrict__ seq)
{
    __shared__ float W1t[H * H];
    __shared__ float gs[8][H];
    __shared__ float tb[8][H];
    int tid = threadIdx.x;
    for (int idx = tid; idx < H * H; idx += 256) {
        int f = idx & 31, k = idx >> 5;
        W1t[k * H + f] = fc1W[f * H + k];
    }
    int n0 = blockIdx.x * 8;
    int nl = tid >> 5, f = tid & 31;
    int g = n0 + nl;
    bool ok = g < G;
    gs[nl][f] = ok ? gpool[g * H + f] : 0.f;
    __syncthreads();
    float z = fc1b[f];
#pragma unroll
    for (int k = 0; k < H; ++k) z += gs[nl][k] * W1t[k * H + f];
    tb[nl][f] = fmaxf(z, 0.f);
    __syncthreads();
    if (ok && f < C) {
        float z2 = fc2b[f];
#pragma unroll
        for (int k = 0; k < H; ++k) z2 += tb[nl][k] * fc2W[f * H + k];
        seq[g * C + f] = z2;
    }
}

// ---------- wave-synchronous bidirectional LSTM ----------
// 1 wave per direction, zero barriers in the time loop.
// WEIGHTS LIVE IN LDS (DS pipe overlaps VALU; registers only hold ~35 temps
// so nothing spills — rounds 3-7 showed the allocator spills reg-resident
// weights to AGPR/scratch at ~2x step cost).
// Gate exchange via __shfl_xor(.,32) + select — verified correct (round 4/7).

#if __has_builtin(__builtin_amdgcn_readlane)
#define RDL(v, k) __int_as_float(__builtin_amdgcn_readlane(__float_as_int(v), (k)))
#else
#define RDL(v, k) __shfl((v), (k), 64)
#endif

#define LOG2E  1.4426950408889634f
#define N2L2E  2.8853900817779268f

#if __has_builtin(__builtin_amdgcn_exp2f) && __has_builtin(__builtin_amdgcn_rcpf)
#define EXP2F(x) __builtin_amdgcn_exp2f(x)
#define RCPF(x)  __builtin_amdgcn_rcpf(x)
#else
#define EXP2F(x) exp2f(x)
#define RCPF(x)  (1.f / (x))
#endif

__device__ __forceinline__ float fsig(float x) {   // 1/(1+e^-x)
    return RCPF(1.f + EXP2F(-LOG2E * x));
}
__device__ __forceinline__ float ftanh(float x) {  // 2/(1+e^-2x) - 1
    return 2.f * RCPF(1.f + EXP2F(-N2L2E * x)) - 1.f;
}

// accumulate 4 k-slots from LDS weights: literal J in [0,7]
#define ACC4L(J)                                                          \
    {                                                                     \
        float4 av = wA[(J) * 64 + lane];                                  \
        float4 bv = wB[(J) * 64 + lane];                                  \
        float h0 = RDL(hval, 4 * (J));                                    \
        float h1 = RDL(hval, 4 * (J) + 1);                                \
        float h2 = RDL(hval, 4 * (J) + 2);                                \
        float h3 = RDL(hval, 4 * (J) + 3);                                \
        z0 = fmaf(av.x, h0, z0); z1 = fmaf(av.y, h1, z1);                 \
        z2 = fmaf(av.z, h2, z2); z3 = fmaf(av.w, h3, z3);                 \
        y0 = fmaf(bv.x, h0, y0); y1 = fmaf(bv.y, h1, y1);                 \
        y2 = fmaf(bv.z, h2, y2); y3 = fmaf(bv.w, h3, y3);                 \
    }

__global__ __launch_bounds__(128, 1) void k_lstm(
    const float* __restrict__ seq,
    const float* __restrict__ Wih_f, const float* __restrict__ Whh_f,
    const float* __restrict__ bih_f, const float* __restrict__ bhh_f,
    const float* __restrict__ Wih_b, const float* __restrict__ Whh_b,
    const float* __restrict__ bih_b, const float* __restrict__ bhh_b,
    const float* __restrict__ redW, const float* __restrict__ redb,
    float* __restrict__ out)
{
    __shared__ float  sq[G * C];
    __shared__ float  hl[2][H];
    __shared__ float4 wl4[2048];   // [dir][ab][k4][lane] float4 = 32 KB
    int tid  = threadIdx.x;
    int dir  = tid >> 6;       // wave 0 = forward, wave 1 = backward
    int lane = tid & 63;

    for (int i = tid; i < G * C; i += 128) sq[i] = seq[i];
    // stage Whh rows into LDS: wl4[d*1024 + ab*512 + k4*64 + l]
    //   = Whh_d[(ab*64 + l)*H + 4*k4 .. +3]
    for (int i = tid; i < 2048; i += 128) {
        int d  = i >> 10;
        int r  = i & 1023;
        int ab = r >> 9;
        int k4 = (r >> 6) & 7;
        int l  = r & 63;
        const float4* src4 = (const float4*)(d ? Whh_b : Whh_f);
        wl4[i] = src4[(ab * 64 + l) * 8 + k4];
    }
    __syncthreads();

    const float* Wih = dir ? Wih_b : Wih_f;
    const float* bih = dir ? bih_b : bih_f;
    const float* bhh = dir ? bhh_b : bhh_f;

    // lane l owns gate rows ra=l (i rows 0..31 | f rows 32..63)
    //                    and rb=l+64 (g rows 64..95 | o rows 96..127)
    int ra = lane;
    int rb = lane + 64;
    bool hi = lane >= 32;

    const float4* wA = &wl4[dir * 1024];        // rows 0..63  (lane-major)
    const float4* wB = &wl4[dir * 1024 + 512];  // rows 64..127

    float wia0 = Wih[ra * C], wia1 = Wih[ra * C + 1];
    float wib0 = Wih[rb * C], wib1 = Wih[rb * C + 1];
    float bza  = bih[ra] + bhh[ra];
    float bzb  = bih[rb] + bhh[rb];

    float hval = 0.f;     // replicated: lane holds h[lane&31]
    float cst  = 0.f;     // replicated cell state

    // software-pipelined sq reads
    int tt0 = dir ? (G - 1) : 0;
    float x0 = sq[tt0 * C];
    float x1 = sq[tt0 * C + 1];

    for (int t = 0; t < G; ++t) {
        int tn = (t + 1 < G) ? (dir ? (G - 2 - t) : (t + 1)) : 0;
        float nx0 = sq[tn * C];
        float nx1 = sq[tn * C + 1];

        float z0 = 0.f, z1 = 0.f, z2 = 0.f, z3 = 0.f;
        float y0 = 0.f, y1 = 0.f, y2 = 0.f, y3 = 0.f;
        ACC4L(0); ACC4L(1); ACC4L(2); ACC4L(3);
        ACC4L(4); ACC4L(5); ACC4L(6); ACC4L(7);
        float za = bza + fmaf(wia0, x0, fmaf(wia1, x1, (z0 + z1) + (z2 + z3)));
        float zb = bzb + fmaf(wib0, x0, fmaf(wib1, x1, (y0 + y1) + (y2 + y3)));

        // za: lanes 0..31 = i-rows, lanes 32..63 = f-rows
        // zb: lanes 0..31 = g-rows, lanes 32..63 = o-rows
        float zax = __shfl_xor(za, 32, 64);
        float zbx = __shfl_xor(zb, 32, 64);
        float zi = hi ? zax : za;
        float zf = hi ? za  : zax;
        float zg = hi ? zbx : zb;
        float zo = hi ? zb  : zbx;

        cst  = fsig(zf) * cst + fsig(zi) * ftanh(zg);
        hval = fsig(zo) * ftanh(cst);

        x0 = nx0; x1 = nx1;
    }

    if (lane < H) hl[dir][lane] = hval;
    __syncthreads();

    if (tid == 0) {
        float v0 = redb[0], v1 = redb[1];
        for (int k = 0; k < H; ++k) {
            v0 += hl[0][k] * redW[k]         + hl[1][k] * redW[H + k];
            v1 += hl[0][k] * redW[2 * H + k] + hl[1][k] * redW[3 * H + k];
        }
        v0 = fmaxf(v0, 0.f);
        v1 = fmaxf(v1, 0.f);
        float m = fmaxf(v0, v1);
        float l = logf(expf(v0 - m) + expf(v1 - m));
        out[0] = v0 - m - l;
        out[1] = v1 - m - l;
    }
}

extern "C" void kernel_launch(void* const* d_in, const int* in_sizes, int n_in,
                              void* d_out, int out_size, void* d_ws, size_t ws_size,
                              hipStream_t stream) {
    const float* x        = (const float*)d_in[0];
    const int*   ei       = (const int*)  d_in[1];
    const int*   batch    = (const int*)  d_in[2];
    const float* gin0_W1  = (const float*)d_in[3];
    const float* gin0_b1  = (const float*)d_in[4];
    const float* gin0_W2  = (const float*)d_in[5];
    const float* gin0_b2  = (const float*)d_in[6];
    const float* bn0_g    = (const float*)d_in[7];
    const float* bn0_b    = (const float*)d_in[8];
    const float* bn0_m    = (const float*)d_in[9];
    const float* bn0_v    = (const float*)d_in[10];
    const float* gin1_W1  = (const float*)d_in[11];
    const float* gin1_b1  = (const float*)d_in[12];
    const float* gin1_W2  = (const float*)d_in[13];
    const float* gin1_b2  = (const float*)d_in[14];
    const float* bn1_g    = (const float*)d_in[15];
    const float* bn1_b    = (const float*)d_in[16];
    const float* bn1_m    = (const float*)d_in[17];
    const float* bn1_v    = (const float*)d_in[18];
    const float* fc1_W    = (const float*)d_in[19];
    const float* fc1_b    = (const float*)d_in[20];
    const float* fc2_W    = (const float*)d_in[21];
    const float* fc2_b    = (const float*)d_in[22];
    const float* Wih_f    = (const float*)d_in[23];
    const float* Whh_f    = (const float*)d_in[24];
    const float* bih_f    = (const float*)d_in[25];
    const float* bhh_f    = (const float*)d_in[26];
    const float* Wih_b    = (const float*)d_in[27];
    const float* Whh_b    = (const float*)d_in[28];
    const float* bih_b    = (const float*)d_in[29];
    const float* bhh_b    = (const float*)d_in[30];
    const float* red_W    = (const float*)d_in[31];
    const float* red_b    = (const float*)d_in[32];

    // workspace layout
    float* ws    = (float*)d_ws;
    float* A     = ws;                          // y buffer   N*H
    float* B     = A + (size_t)N_NODES * H;     // agg buffer N*H
    float* gpool = B + (size_t)N_NODES * H;     // G*H
    float* seq   = gpool + (size_t)G * H;       // G*C
    int*   rowptr = (int*)(seq + (size_t)G * C);        // N+1
    int*   cursor = rowptr + (N_NODES + 1);             // N
    int*   bsum   = cursor + N_NODES;                   // 1024
    int*   elist  = bsum + 1024;                        // E

    int nblk_nodes = (N_NODES + 7) / 8;          // 12500 (8 nodes/block)
    int nblk_edges = (N_EDGES + 255) / 256;      // 6250
    int nblk_scan  = (N_NODES + 255) / 256;      // 391
    int nblk_agg   = (N_NODES * 8 + 255) / 256;  // 3125

    // ---- CSR build (once; reused by both layers)
    k_zero_i<<<nblk_scan, 256, 0, stream>>>(rowptr, N_NODES);
    k_hist<<<nblk_edges, 256, 0, stream>>>(ei, rowptr);
    k_scan1<<<nblk_scan, 256, 0, stream>>>(rowptr, bsum);
    k_scan2<<<1, 512, 0, stream>>>(bsum, nblk_scan);
    k_scan3<<<nblk_scan, 256, 0, stream>>>(rowptr, bsum, cursor);
    k_scatter<<<nblk_edges, 256, 0, stream>>>(ei, cursor, elist);

    k_zero_f<<<(G * H + 255) / 256, 256, 0, stream>>>(gpool, G * H);

    // ---- layer 0
    k_xform0<<<nblk_nodes, 256, 0, stream>>>(x, gin0_W1, A);
    k_agg<<<nblk_agg, 256, 0, stream>>>(rowptr, elist, A, B);
    k_mlp0<<<nblk_nodes, 256, 0, stream>>>(B, gin0_b1, gin0_W2, gin0_b2,
                                           bn0_g, bn0_b, bn0_m, bn0_v,
                                           gin1_W1, A);
    // ---- layer 1
    k_agg<<<nblk_agg, 256, 0, stream>>>(rowptr, elist, A, B);
    k_mlp1_pool<<<nblk_nodes, 256, 0, stream>>>(B, batch, gin1_b1, gin1_W2,
                                                gin1_b2, bn1_g, bn1_b, bn1_m,
                                                bn1_v, gpool);
    // ---- dense tail
    k_fc<<<(G + 7) / 8, 256, 0, stream>>>(gpool, fc1_W, fc1_b, fc2_W, fc2_b, seq);
    k_lstm<<<1, 128, 0, stream>>>(seq, Wih_f, Whh_f, bih_f, bhh_f,
                                  Wih_b, Whh_b, bih_b, bhh_b,
                                  red_W, red_b, (float*)d_out);
}